// Round 11
// baseline (293.999 us; speedup 1.0000x reference)
//
#include <hip/hip_runtime.h>

// ProteinGCN: 2x GCNConv(+relu) + FC head. N=100k, E=1.6M, 64->128->64->1.
// Round 16: r15's W-LDS-staging regressed (gemm not weight-bound) ->
// reverted. Last untested gather mechanism: wave divergence. Each wave owns
// 8 nodes, Poisson(16) degrees, runs to the MAX node's iterations
// (E[max ceil(d/8)] ~3-4 vs mean 2 -> ~1.6x issue waste) -- consistent with
// "nothing saturated, immovable by byte/instr levers". Fix: degree-sorted
// node permutation (64-bin counting sort; degree known in k_bucket; both
// gathers process perm[idx], outputs still indexed by node id -> numerics
// bit-identical). Discriminator: null => outstanding-request floor =>
// declare. CSR: r14 two-level bucket + tcnt + fused prescale. Gathers: fp16
// sliced XCD-pinned (r12). GEMMs: split-bf16 MFMA, direct W reads (r14).

constexpr int NN = 100000;
constexpr int NE = 1600000;
constexpr int D0 = 64;   // input dim
constexpr int D1 = 128;  // hidden 1
constexpr int D2 = 64;   // hidden 2
constexpr int NB = (NN + 255) / 256;  // 391 buckets
constexpr int TILE = 8192;            // edges per k_part/k_bcount block
constexpr int NT = (NE + TILE - 1) / TILE;  // 196 tiles
constexpr int H1STRIDE = 132;         // h1 LDS row stride (u32)
constexpr int NH = NN / 2;            // 50000 nodes per XCD-half

typedef unsigned short u16;
typedef unsigned int u32;
typedef __attribute__((ext_vector_type(8))) short short8;  // 8 bf16 (4 VGPR)
typedef __attribute__((ext_vector_type(4))) float f32x4;
typedef _Float16 h4 __attribute__((ext_vector_type(4)));   // 4 fp16 = 8 B

// ---------------- helpers ----------------

__device__ __forceinline__ float4 scale4(const float4& a, float s) {
    return float4{a.x * s, a.y * s, a.z * s, a.w * s};
}

__device__ __forceinline__ void addh8(float4& a, float4& b, uint4 u) {
    h4 h0 = *(h4*)&u.x;
    h4 h1 = *(h4*)&u.z;
    a.x += (float)h0[0]; a.y += (float)h0[1]; a.z += (float)h0[2]; a.w += (float)h0[3];
    b.x += (float)h1[0]; b.y += (float)h1[1]; b.z += (float)h1[2]; b.w += (float)h1[3];
}

__device__ __forceinline__ uint2 packh4(const float4& v) {
    h4 h;
    h[0] = (_Float16)v.x; h[1] = (_Float16)v.y;
    h[2] = (_Float16)v.z; h[3] = (_Float16)v.w;
    return *(uint2*)&h;
}

__device__ __forceinline__ void xor_reduce8(float4& a, float4& b, int mask) {
    a.x += __shfl_xor(a.x, mask, 64);
    a.y += __shfl_xor(a.y, mask, 64);
    a.z += __shfl_xor(a.z, mask, 64);
    a.w += __shfl_xor(a.w, mask, 64);
    b.x += __shfl_xor(b.x, mask, 64);
    b.y += __shfl_xor(b.y, mask, 64);
    b.z += __shfl_xor(b.z, mask, 64);
    b.w += __shfl_xor(b.w, mask, 64);
}

// bf16 RNE conversion + back
__device__ __forceinline__ u16 f2bf(float f) {
    u32 u = __float_as_uint(f);
    return (u16)((u + 0x7fffu + ((u >> 16) & 1u)) >> 16);
}
__device__ __forceinline__ float bf2f(u16 h) {
    return __uint_as_float(((u32)h) << 16);
}

// ---------------- weight pre-split + counter zero (merged) ----------------
// Blocks 0..31: split W1/W2 into hi/lo bf16 B-fragments. Block 32: zero
// gbcnt (512) + gdeg (64).
// B-fragment (16x16x32 bf16): lane l holds B[k][col], col=l&15, k=(l>>4)*8+j.
__global__ __launch_bounds__(256) void k_splitW(const float* __restrict__ W1,
                                                const float* __restrict__ W2,
                                                u16* __restrict__ W1h, u16* __restrict__ W1l,
                                                u16* __restrict__ W2h, u16* __restrict__ W2l,
                                                int* __restrict__ gbcnt,
                                                int* __restrict__ gdeg) {
    if (blockIdx.x == 32) {
        int t = threadIdx.x;
        gbcnt[t] = 0;
        gbcnt[t + 256] = 0;
        if (t < 64) gdeg[t] = 0;
        return;
    }
    int i = blockIdx.x * 256 + threadIdx.x;  // 0..8191
    int j = i & 7;
    int l = (i >> 3) & 63;
    int ts = i >> 9;                 // 0..15
    int kf = ((l >> 4) << 3) + j;    // k within 32-step
    int cl = l & 15;
    {   // W1 [64][128]: ts = s*8 + t
        int s = ts >> 3, t = ts & 7;
        float w = W1[(s * 32 + kf) * D1 + t * 16 + cl];
        u16 h = f2bf(w);
        W1h[i] = h;
        W1l[i] = f2bf(w - bf2f(h));
    }
    {   // W2 [128][64]: ts = s*4 + t
        int s = ts >> 2, t = ts & 3;
        float w = W2[(s * 32 + kf) * D2 + t * 16 + cl];
        u16 h = f2bf(w);
        W2h[i] = h;
        W2l[i] = f2bf(w - bf2f(h));
    }
}

// ---------------- bucket count: per-tile LDS hist -> gbcnt + tcnt ----------------
__global__ __launch_bounds__(256) void k_bcount(const int* __restrict__ dst,
                                                int* __restrict__ gbcnt,
                                                int* __restrict__ tcnt) {
    __shared__ int cnt_s[NB];
    int tid = threadIdx.x;
    int e0 = blockIdx.x * TILE;
    int ecnt = NE - e0 < TILE ? NE - e0 : TILE;
    for (int i = tid; i < NB; i += 256) cnt_s[i] = 0;
    __syncthreads();
    for (int i = tid; i < ecnt; i += 256)
        atomicAdd(&cnt_s[dst[e0 + i] >> 8], 1);
    __syncthreads();
    int* trow = tcnt + (size_t)blockIdx.x * NB;
    for (int i = tid; i < NB; i += 256) {
        int c = cnt_s[i];
        trow[i] = c;
        if (c) atomicAdd(&gbcnt[i], c);
    }
}

// scan 391 bucket counts -> bucket bases (bsum, bsum[NB]=NE) + part cursors
__global__ __launch_bounds__(512) void k_scan_bsum(const int* __restrict__ gbcnt,
                                                   int* __restrict__ bsum,
                                                   int* __restrict__ gcur) {
    __shared__ int s[512];
    int tid = threadIdx.x;
    int v = (tid < NB) ? gbcnt[tid] : 0;
    s[tid] = v;
    __syncthreads();
#pragma unroll
    for (int off = 1; off < 512; off <<= 1) {
        int t = (tid >= off) ? s[tid - off] : 0;
        __syncthreads();
        s[tid] += t;
        __syncthreads();
    }
    int ex = s[tid] - v;  // exclusive scan
    if (tid <= NB) bsum[tid] = ex;   // bsum[NB] == NE
    if (tid < NB) gcur[tid] = ex;
}

// ---- partition edges into dst-buckets using precomputed tile counts ----
__global__ __launch_bounds__(256) void k_part(const int* __restrict__ src,
                                              const int* __restrict__ dst,
                                              const int* __restrict__ tcnt,
                                              int* __restrict__ gcur,
                                              unsigned* __restrict__ packed) {
    __shared__ int gbase_s[NB];
    __shared__ int cur_s[NB];
    int tid = threadIdx.x;
    int e0 = blockIdx.x * TILE;
    int ecnt = NE - e0 < TILE ? NE - e0 : TILE;
    const int* trow = tcnt + (size_t)blockIdx.x * NB;
    for (int i = tid; i < NB; i += 256) {
        int c = trow[i];
        gbase_s[i] = c ? atomicAdd(&gcur[i], c) : 0;
        cur_s[i] = 0;
    }
    __syncthreads();
    for (int i = tid; i < ecnt; i += 256) {
        int d = dst[e0 + i];
        int s = src[e0 + i];
        int b = d >> 8;
        int slot = atomicAdd(&cur_s[b], 1);
        packed[gbase_s[b] + slot] = ((unsigned)(d & 255) << 24) | (unsigned)s;
    }
}

// ---- one block per bucket: node hist -> dinv + rowptr, scatter col, prescale ----
// Also accumulates the global degree histogram gdeg[64] (clamped bins) for
// the degree-sorted permutation.
__global__ __launch_bounds__(256) void k_bucket(const int* __restrict__ bsum,
                                                const unsigned* __restrict__ packed,
                                                const float* __restrict__ x,
                                                int* __restrict__ rowptr,
                                                float* __restrict__ dinv,
                                                int* __restrict__ col,
                                                u16* __restrict__ xs,
                                                int* __restrict__ gdeg) {
    __shared__ int hist[256];
    __shared__ int s[256];
    __shared__ int cur[256];
    __shared__ float dinv_s[256];
    __shared__ int dh[64];
    int b = blockIdx.x;
    int tid = threadIdx.x;
    int e0 = bsum[b], e1 = bsum[b + 1];
    hist[tid] = 0;
    if (tid < 64) dh[tid] = 0;
    __syncthreads();
    for (int e = e0 + tid; e < e1; e += 256)
        atomicAdd(&hist[packed[e] >> 24], 1);
    __syncthreads();
    int v = hist[tid];
    int n = (b << 8) + tid;
    float di = rsqrtf((float)(v + 1));
    dinv_s[tid] = di;
    if (n < NN) {
        dinv[n] = di;
        atomicAdd(&dh[v > 63 ? 63 : v], 1);
    }
    // exclusive scan of per-node counts
    s[tid] = v;
    __syncthreads();
#pragma unroll
    for (int off = 1; off < 256; off <<= 1) {
        int t = (tid >= off) ? s[tid - off] : 0;
        __syncthreads();
        s[tid] += t;
        __syncthreads();
    }
    if (tid < 64 && dh[tid]) atomicAdd(&gdeg[tid], dh[tid]);
    int base = e0 + s[tid] - v;
    if (n <= NN) rowptr[n] = base;   // n==NN (last bucket) lands on e1==NE
    cur[tid] = base;
    __syncthreads();
    for (int e = e0 + tid; e < e1; e += 256) {
        unsigned p = packed[e];
        int pos = atomicAdd(&cur[p >> 24], 1);
        col[pos] = (int)((p & 0xFFFFFFu) << 5);  // src * 32 byte offset
    }
    // fused prescale for this bucket's nodes
    int n_hi = NN - (b << 8);
    if (n_hi > 256) n_hi = 256;
    for (int i = tid; i < n_hi * 16; i += 256) {
        int nl = i >> 4;
        int k4 = i & 15;
        int q = k4 >> 2;
        int nn = (b << 8) + nl;
        uint2 w = packh4(scale4(((const float4*)x)[(size_t)nn * 16 + k4], dinv_s[nl]));
        ((uint2*)xs)[((size_t)q * NN + nn) * 4 + (k4 & 3)] = w;
    }
}

// ---- 64-bin exclusive scan of degree histogram -> global cursors ----
__global__ __launch_bounds__(64) void k_scan_deg(const int* __restrict__ gdeg,
                                                 int* __restrict__ dcur) {
    int tid = threadIdx.x;  // 0..63
    int v = gdeg[tid];
    int sum = v;
#pragma unroll
    for (int off = 1; off < 64; off <<= 1) {
        int t = __shfl_up(sum, off, 64);
        if (tid >= off) sum += t;
    }
    dcur[tid] = sum - v;  // exclusive
}

// ---- scatter nodes into degree-sorted permutation (two-phase, per block) ----
__global__ __launch_bounds__(256) void k_perm(const int* __restrict__ rowptr,
                                              int* __restrict__ dcur,
                                              int* __restrict__ perm) {
    __shared__ int dh[64];
    __shared__ int dbase[64];
    int tid = threadIdx.x;
    int n = blockIdx.x * 256 + tid;
    if (tid < 64) dh[tid] = 0;
    __syncthreads();
    int bin = 0, slot = 0;
    bool valid = n < NN;
    if (valid) {
        int d = rowptr[n + 1] - rowptr[n];
        bin = d > 63 ? 63 : d;
        slot = atomicAdd(&dh[bin], 1);
    }
    __syncthreads();
    if (tid < 64) dbase[tid] = dh[tid] ? atomicAdd(&dcur[tid], dh[tid]) : 0;
    __syncthreads();
    if (valid) perm[dbase[bin] + slot] = n;
}

// ---------------- layer-1 sliced gather (degree-sorted order) ----------------
// Slice s pinned to XCDs {2s,2s+1} via blockIdx%8; each XCD takes one
// perm-index half. Wave owns 8 perm-consecutive nodes (uniform degree).
// agg layout: [4][NN][16] f32.
__global__ __launch_bounds__(256) void k_gather1s(const int* __restrict__ rowptr,
                                                  const int* __restrict__ colb,
                                                  const int* __restrict__ perm,
                                                  const u16* __restrict__ xs,
                                                  const float* __restrict__ dinv,
                                                  float* __restrict__ agg) {
    int bid = blockIdx.x;
    int sh = bid & 7;
    int s = sh >> 1, h = sh & 1;
    int tid = threadIdx.x;
    int lane = tid & 63;
    int wv = tid >> 6;
    int idx = h * NH + (bid >> 3) * 32 + wv * 8 + (lane >> 3);
    if (idx >= (h + 1) * NH) return;
    int n = perm[idx];
    int half = lane & 1;
    int es = (lane >> 1) & 3;
    int r0 = rowptr[n], r1 = rowptr[n + 1];
    const char* base = (const char*)xs + (size_t)s * NN * 32 + half * 16;
    float4 a{0, 0, 0, 0}, b{0, 0, 0, 0};
    if (es == 0) addh8(a, b, *(const uint4*)(base + (size_t)n * 32));  // self loop
    int e = r0 + es;
    for (; e + 4 < r1; e += 8) {
        int c0 = colb[e];
        int c1 = colb[e + 4];
        uint4 v0 = *(const uint4*)(base + c0);
        uint4 v1 = *(const uint4*)(base + c1);
        addh8(a, b, v0);
        addh8(a, b, v1);
    }
    for (; e < r1; e += 4)
        addh8(a, b, *(const uint4*)(base + colb[e]));
    xor_reduce8(a, b, 2);
    xor_reduce8(a, b, 4);
    if (es == 0) {
        float di = dinv[n];
        float* ag = agg + ((size_t)s * NN + n) * 16 + half * 8;
        *(float4*)ag = scale4(a, di);
        *(float4*)(ag + 4) = scale4(b, di);
    }
}

// ---------------- fused GEMM1 + GEMM2 via split-bf16 MFMA ----------------
// h1 = relu(agg @ W1 + b1)   (64 -> 128, packed hi/lo bf16 in LDS)
// y2 slices = fp16((h1 @ W2) * dinv)  (128 -> 64), layout [4][NN][16]
// agg read is slice-major: k = q*16 + c  ->  agg[(q*NN+n)*16 + c].
__global__ __launch_bounds__(256) void k_gemm12(const float* __restrict__ agg,
                                                const u16* __restrict__ W1h,
                                                const u16* __restrict__ W1l,
                                                const float* __restrict__ b1,
                                                const u16* __restrict__ W2h,
                                                const u16* __restrict__ W2l,
                                                const float* __restrict__ dinv,
                                                u16* __restrict__ y2) {
    __shared__ u32 h1s[64 * H1STRIDE];  // packed (hi | lo<<16), 33.8 KB
    int tid = threadIdx.x;
    int l = tid & 63;
    int wv = tid >> 6;
    int n_base = blockIdx.x * 64;
    int row_a = l & 15;           // A-operand row within 16-tile
    int kg = (l >> 4) << 3;       // k offset within 32-step: 0,8,16,24
    int crow = (l >> 4) * 4;      // C/D row base: (lane>>4)*4

    // ---- phase A: h1 = relu(agg @ W1 + b1) ----
    short8 Ah[2], Al[2];
#pragma unroll
    for (int s = 0; s < 2; ++s) {
        int an = n_base + wv * 16 + row_a;
        if (an >= NN) an = NN - 1;  // clamp: dup rows, outputs discarded
        int q = (s * 32 + kg) >> 4;      // agg slice
        int off = kg & 8;                // col offset within slice
        const float* ap = agg + ((size_t)q * NN + an) * 16 + off;
        f32x4 v0 = *(const f32x4*)ap;
        f32x4 v1 = *(const f32x4*)(ap + 4);
#pragma unroll
        for (int j = 0; j < 4; ++j) {
            u16 h0 = f2bf(v0[j]);
            Ah[s][j] = (short)h0;
            Al[s][j] = (short)f2bf(v0[j] - bf2f(h0));
            u16 h1b = f2bf(v1[j]);
            Ah[s][j + 4] = (short)h1b;
            Al[s][j + 4] = (short)f2bf(v1[j] - bf2f(h1b));
        }
    }
#pragma unroll
    for (int t = 0; t < 8; ++t) {
        f32x4 acc = {0.f, 0.f, 0.f, 0.f};
#pragma unroll
        for (int s = 0; s < 2; ++s) {
            short8 Bh = *(const short8*)(W1h + ((size_t)(s * 8 + t) * 64 + l) * 8);
            short8 Bl = *(const short8*)(W1l + ((size_t)(s * 8 + t) * 64 + l) * 8);
            acc = __builtin_amdgcn_mfma_f32_16x16x32_bf16(Ah[s], Bh, acc, 0, 0, 0);
            acc = __builtin_amdgcn_mfma_f32_16x16x32_bf16(Ah[s], Bl, acc, 0, 0, 0);
            acc = __builtin_amdgcn_mfma_f32_16x16x32_bf16(Al[s], Bh, acc, 0, 0, 0);
        }
        // epilogue: +b1, relu, split-pack to LDS (C/D: row=(l>>4)*4+r, col=l&15)
        float bb = b1[t * 16 + (l & 15)];
        int kcol = t * 16 + (l & 15);  // h1 feature index = GEMM2 k
#pragma unroll
        for (int r = 0; r < 4; ++r) {
            int row = wv * 16 + crow + r;  // node row in 64-tile
            float v = fmaxf(acc[r] + bb, 0.f);
            u16 h = f2bf(v);
            u16 lo = f2bf(v - bf2f(h));
            h1s[row * H1STRIDE + kcol] = (u32)h | ((u32)lo << 16);
        }
    }
    __syncthreads();

    // ---- phase B: y2 slices = fp16((h1 @ W2) * dinv) ----
    short8 A2h[4], A2l[4];
#pragma unroll
    for (int s = 0; s < 4; ++s) {
        int row = wv * 16 + row_a;
        const u32* hp = &h1s[row * H1STRIDE + s * 32 + kg];
        uint4 p0 = *(const uint4*)hp;
        uint4 p1 = *(const uint4*)(hp + 4);
        u32 pv[8] = {p0.x, p0.y, p0.z, p0.w, p1.x, p1.y, p1.z, p1.w};
#pragma unroll
        for (int j = 0; j < 8; ++j) {
            A2h[s][j] = (short)(pv[j] & 0xffffu);
            A2l[s][j] = (short)(pv[j] >> 16);
        }
    }
#pragma unroll
    for (int t = 0; t < 4; ++t) {
        f32x4 acc = {0.f, 0.f, 0.f, 0.f};
#pragma unroll
        for (int s = 0; s < 4; ++s) {
            short8 Bh = *(const short8*)(W2h + ((size_t)(s * 4 + t) * 64 + l) * 8);
            short8 Bl = *(const short8*)(W2l + ((size_t)(s * 4 + t) * 64 + l) * 8);
            acc = __builtin_amdgcn_mfma_f32_16x16x32_bf16(A2h[s], Bh, acc, 0, 0, 0);
            acc = __builtin_amdgcn_mfma_f32_16x16x32_bf16(A2h[s], Bl, acc, 0, 0, 0);
            acc = __builtin_amdgcn_mfma_f32_16x16x32_bf16(A2l[s], Bh, acc, 0, 0, 0);
        }
        // t == 16-feature slice of y2
#pragma unroll
        for (int r = 0; r < 4; ++r) {
            int n = n_base + wv * 16 + crow + r;
            if (n < NN) {
                _Float16 hf = (_Float16)(acc[r] * dinv[n]);
                y2[((size_t)t * NN + n) * 16 + (l & 15)] = *(u16*)&hf;
            }
        }
    }
}

// ---------------- layer-2 sliced gather + per-slice partial FC head ----------------
// partial[s][n] = sum_{c in slice s} relu((self+sum neigh)*di + b2)[c] * Wfc[c]
__global__ __launch_bounds__(256) void k_gather2s(const int* __restrict__ rowptr,
                                                  const int* __restrict__ colb,
                                                  const int* __restrict__ perm,
                                                  const u16* __restrict__ y2,
                                                  const float* __restrict__ dinv,
                                                  const float* __restrict__ b2,
                                                  const float* __restrict__ Wfc,
                                                  float* __restrict__ partial) {
    int bid = blockIdx.x;
    int sh = bid & 7;
    int s = sh >> 1, h = sh & 1;
    int tid = threadIdx.x;
    int lane = tid & 63;
    int wv = tid >> 6;
    int idx = h * NH + (bid >> 3) * 32 + wv * 8 + (lane >> 3);
    if (idx >= (h + 1) * NH) return;
    int n = perm[idx];
    int half = lane & 1;
    int es = (lane >> 1) & 3;
    int r0 = rowptr[n], r1 = rowptr[n + 1];
    const char* base = (const char*)y2 + (size_t)s * NN * 32 + half * 16;
    float4 a{0, 0, 0, 0}, b{0, 0, 0, 0};
    if (es == 0) addh8(a, b, *(const uint4*)(base + (size_t)n * 32));  // self loop
    int e = r0 + es;
    for (; e + 4 < r1; e += 8) {
        int c0 = colb[e];
        int c1 = colb[e + 4];
        uint4 v0 = *(const uint4*)(base + c0);
        uint4 v1 = *(const uint4*)(base + c1);
        addh8(a, b, v0);
        addh8(a, b, v1);
    }
    for (; e < r1; e += 4)
        addh8(a, b, *(const uint4*)(base + colb[e]));
    xor_reduce8(a, b, 2);
    xor_reduce8(a, b, 4);
    // lanes es==0 hold the 8-feature sums for (slice s, half)
    float di = dinv[n];
    int fo = s * 16 + half * 8;
    float4 b0 = *(const float4*)(b2 + fo);
    float4 b1v = *(const float4*)(b2 + fo + 4);
    float4 w0 = *(const float4*)(Wfc + fo);
    float4 w1 = *(const float4*)(Wfc + fo + 4);
    float p = fmaxf(fmaf(a.x, di, b0.x), 0.f) * w0.x
            + fmaxf(fmaf(a.y, di, b0.y), 0.f) * w0.y
            + fmaxf(fmaf(a.z, di, b0.z), 0.f) * w0.z
            + fmaxf(fmaf(a.w, di, b0.w), 0.f) * w0.w
            + fmaxf(fmaf(b.x, di, b1v.x), 0.f) * w1.x
            + fmaxf(fmaf(b.y, di, b1v.y), 0.f) * w1.y
            + fmaxf(fmaf(b.z, di, b1v.z), 0.f) * w1.z
            + fmaxf(fmaf(b.w, di, b1v.w), 0.f) * w1.w;
    p += __shfl_xor(p, 1, 64);  // combine halves
    if ((lane & 7) == 0 && es == 0) partial[(size_t)s * NN + n] = p;
}

// ---------------- head: sum 4 slice partials + bfc ----------------
__global__ __launch_bounds__(256) void k_head(const float* __restrict__ partial,
                                              const float* __restrict__ bfc,
                                              float* __restrict__ out) {
    int i = blockIdx.x * 256 + threadIdx.x;
    if (i >= NN) return;
    out[i] = partial[i] + partial[NN + i] + partial[2 * NN + i]
           + partial[3 * NN + i] + bfc[0];
}

extern "C" void kernel_launch(void* const* d_in, const int* in_sizes, int n_in,
                              void* d_out, int out_size, void* d_ws, size_t ws_size,
                              hipStream_t stream) {
    const float* x   = (const float*)d_in[0];
    const int*   ei  = (const int*)d_in[1];   // [2, E] int
    const float* W1  = (const float*)d_in[2];
    const float* b1  = (const float*)d_in[3];
    const float* W2  = (const float*)d_in[4];
    const float* b2  = (const float*)d_in[5];
    const float* Wfc = (const float*)d_in[6];
    const float* bfc = (const float*)d_in[7];
    float* out = (float*)d_out;

    const int* src = ei;
    const int* dst = ei + NE;

    char* ws = (char*)d_ws;
    size_t o = 0;
    auto alloc = [&](size_t bytes) { char* p = ws + o; o += (bytes + 255) & ~size_t(255); return p; };
    int*   scratch = (int*)alloc(NN * 4);      // 400 KB: gbcnt + W-splits + tcnt + gdeg/dcur
    int*   rowptr = (int*)alloc((NN + 1) * 4);
    int*   bsum   = (int*)alloc(512 * 4);
    int*   gcur   = (int*)alloc(NB * 4);
    float* dinv   = (float*)alloc(NN * 4);
    int*   col    = (int*)alloc((size_t)NE * 4);
    int*   perm   = (int*)alloc(NN * 4);                 // degree-sorted node order
    u16*   xs     = (u16*)alloc((size_t)NN * D0 * 2);    // 12.8 MB fp16 (4 slices)
    float* agg1x  = (float*)alloc((size_t)NN * D0 * 4);  // 25.6 MB fp32 (4 slices)
    u16*   y2     = (u16*)alloc((size_t)NN * D2 * 2);    // 12.8 MB fp16 (4 slices)
    float* partial= (float*)alloc((size_t)NN * 4 * 4);   // 1.6 MB
    unsigned* packed = (unsigned*)agg1x;  // dead before k_gather1s writes agg
    // carve scratch: gbcnt (512) + 4 x 16 KB weight splits + tcnt + gdeg + dcur
    int* gbcnt = scratch;
    u16* W1h = (u16*)(scratch + 512);
    u16* W1l = W1h + 8192;
    u16* W2h = W1l + 8192;
    u16* W2l = W2h + 8192;
    int* tcnt = scratch + 512 + 16384;        // 196*391 = 76636 ints
    int* gdeg = tcnt + (size_t)NT * NB;       // 64 ints (ends < 100000 ints)
    int* dcur = gdeg + 64;                    // 64 ints

    const int GB = 8 * ((NH + 31) / 32);    // 12504 blocks: slice-pinned gathers

    k_splitW    <<<33, 256, 0, stream>>>(W1, W2, W1h, W1l, W2h, W2l, gbcnt, gdeg);
    k_bcount    <<<NT, 256, 0, stream>>>(dst, gbcnt, tcnt);
    k_scan_bsum <<<1, 512, 0, stream>>>(gbcnt, bsum, gcur);
    k_part      <<<NT, 256, 0, stream>>>(src, dst, tcnt, gcur, packed);
    k_bucket    <<<NB, 256, 0, stream>>>(bsum, packed, x, rowptr, dinv, col, xs, gdeg);
    k_scan_deg  <<<1, 64, 0, stream>>>(gdeg, dcur);
    k_perm      <<<NB, 256, 0, stream>>>(rowptr, dcur, perm);

    k_gather1s  <<<GB, 256, 0, stream>>>(rowptr, col, perm, xs, dinv, agg1x);
    k_gemm12    <<<(NN + 63) / 64, 256, 0, stream>>>(agg1x, W1h, W1l, b1, W2h, W2l, dinv, y2);
    k_gather2s  <<<GB, 256, 0, stream>>>(rowptr, col, perm, y2, dinv, b2, Wfc, partial);
    k_head      <<<(NN + 255) / 256, 256, 0, stream>>>(partial, bfc, out);
}

// Round 12
// 249.048 us; speedup vs baseline: 1.1805x; 1.1805x over previous
//
#include <hip/hip_runtime.h>

// ProteinGCN: 2x GCNConv(+relu) + FC head. N=100k, E=1.6M, 64->128->64->1.
// Round 17: REVERT to the measured-best r12 structure (246.9us). r16's
// degree-perm regressed (294us: permutation broke dst-side streaming,
// FETCH 36->128MB; balance itself bought 0 -- 8th falsified gather lever).
// Gather floor is ~16-18 cy/edge/CU, invariant under: bytes/2, bytes/4,
// instr/2, unroll x4, 32b addressing, XCD-L2 pinning, int8 rows, degree
// balance. Fill (44us) is the harness workspace re-poison at HBM roofline.
// CSR: two-level bucket (r8). Gathers: fp16 sliced, slice s -> XCDs
// {2s,2s+1} (r12). GEMMs: split-bf16 MFMA (r6/7), fp16 y2 slices (r9/12).

constexpr int NN = 100000;
constexpr int NE = 1600000;
constexpr int D0 = 64;   // input dim
constexpr int D1 = 128;  // hidden 1
constexpr int D2 = 64;   // hidden 2
constexpr int NB = (NN + 255) / 256;  // 391 buckets
constexpr int TILE = 8192;            // edges per k_part/k_bcount block
constexpr int H1STRIDE = 132;         // h1 LDS row stride (u32)
constexpr int NH = NN / 2;            // 50000 nodes per XCD-half

typedef unsigned short u16;
typedef unsigned int u32;
typedef __attribute__((ext_vector_type(8))) short short8;  // 8 bf16 (4 VGPR)
typedef __attribute__((ext_vector_type(4))) float f32x4;
typedef _Float16 h4 __attribute__((ext_vector_type(4)));   // 4 fp16 = 8 B

// ---------------- CSR build ----------------

__global__ __launch_bounds__(256) void k_zero_b(int* __restrict__ g) {
    int i = blockIdx.x * 256 + threadIdx.x;
    if (i < 512) g[i] = 0;
}

// per-tile LDS histogram of dst-buckets -> global bucket counts
__global__ __launch_bounds__(256) void k_bcount(const int* __restrict__ dst,
                                                int* __restrict__ gbcnt) {
    __shared__ int cnt_s[NB];
    int tid = threadIdx.x;
    int e0 = blockIdx.x * TILE;
    int ecnt = NE - e0 < TILE ? NE - e0 : TILE;
    for (int i = tid; i < NB; i += 256) cnt_s[i] = 0;
    __syncthreads();
    for (int i = tid; i < ecnt; i += 256)
        atomicAdd(&cnt_s[dst[e0 + i] >> 8], 1);
    __syncthreads();
    for (int i = tid; i < NB; i += 256) {
        int c = cnt_s[i];
        if (c) atomicAdd(&gbcnt[i], c);
    }
}

// scan 391 bucket counts -> bucket bases (bsum, bsum[NB]=NE) + part cursors
__global__ __launch_bounds__(512) void k_scan_bsum(const int* __restrict__ gbcnt,
                                                   int* __restrict__ bsum,
                                                   int* __restrict__ gcur) {
    __shared__ int s[512];
    int tid = threadIdx.x;
    int v = (tid < NB) ? gbcnt[tid] : 0;
    s[tid] = v;
    __syncthreads();
#pragma unroll
    for (int off = 1; off < 512; off <<= 1) {
        int t = (tid >= off) ? s[tid - off] : 0;
        __syncthreads();
        s[tid] += t;
        __syncthreads();
    }
    int ex = s[tid] - v;  // exclusive scan
    if (tid <= NB) bsum[tid] = ex;   // bsum[NB] == NE
    if (tid < NB) gcur[tid] = ex;
}

// ---- partition edges into dst-buckets, packed (dl<<24)|src ----
__global__ __launch_bounds__(256) void k_part(const int* __restrict__ src,
                                              const int* __restrict__ dst,
                                              int* __restrict__ gcur,
                                              unsigned* __restrict__ packed) {
    __shared__ int cnt_s[NB];
    __shared__ int gbase_s[NB];
    __shared__ int cur_s[NB];
    int tid = threadIdx.x;
    int e0 = blockIdx.x * TILE;
    int ecnt = NE - e0 < TILE ? NE - e0 : TILE;
    for (int i = tid; i < NB; i += 256) cnt_s[i] = 0;
    __syncthreads();
    for (int i = tid; i < ecnt; i += 256)
        atomicAdd(&cnt_s[dst[e0 + i] >> 8], 1);
    __syncthreads();
    for (int i = tid; i < NB; i += 256) {
        int c = cnt_s[i];
        gbase_s[i] = c ? atomicAdd(&gcur[i], c) : 0;
        cur_s[i] = 0;
    }
    __syncthreads();
    for (int i = tid; i < ecnt; i += 256) {
        int d = dst[e0 + i];
        int s = src[e0 + i];
        int b = d >> 8;
        int slot = atomicAdd(&cur_s[b], 1);
        packed[gbase_s[b] + slot] = ((unsigned)(d & 255) << 24) | (unsigned)s;
    }
}

// ---- one block per bucket: node histogram -> dinv + rowptr, scatter col ----
// col stores BYTE offsets (src*32): slice tables are 32 B/row.
__global__ __launch_bounds__(256) void k_bucket(const int* __restrict__ bsum,
                                                const unsigned* __restrict__ packed,
                                                int* __restrict__ rowptr,
                                                float* __restrict__ dinv,
                                                int* __restrict__ col) {
    __shared__ int hist[256];
    __shared__ int s[256];
    __shared__ int cur[256];
    int b = blockIdx.x;
    int tid = threadIdx.x;
    int e0 = bsum[b], e1 = bsum[b + 1];
    hist[tid] = 0;
    __syncthreads();
    for (int e = e0 + tid; e < e1; e += 256)
        atomicAdd(&hist[packed[e] >> 24], 1);
    __syncthreads();
    int v = hist[tid];
    int n = (b << 8) + tid;
    if (n < NN) dinv[n] = rsqrtf((float)(v + 1));
    // exclusive scan of per-node counts
    s[tid] = v;
    __syncthreads();
#pragma unroll
    for (int off = 1; off < 256; off <<= 1) {
        int t = (tid >= off) ? s[tid - off] : 0;
        __syncthreads();
        s[tid] += t;
        __syncthreads();
    }
    int base = e0 + s[tid] - v;
    if (n <= NN) rowptr[n] = base;   // n==NN (last bucket) lands on e1==NE
    cur[tid] = base;
    __syncthreads();
    for (int e = e0 + tid; e < e1; e += 256) {
        unsigned p = packed[e];
        int pos = atomicAdd(&cur[p >> 24], 1);
        col[pos] = (int)((p & 0xFFFFFFu) << 5);  // src * 32 byte offset
    }
}

// ---------------- helpers ----------------

__device__ __forceinline__ float4 scale4(const float4& a, float s) {
    return float4{a.x * s, a.y * s, a.z * s, a.w * s};
}

// add 8 fp16 (uint4) into two float4 accumulators
__device__ __forceinline__ void addh8(float4& a, float4& b, uint4 u) {
    h4 h0 = *(h4*)&u.x;   // u.x,u.y
    h4 h1 = *(h4*)&u.z;   // u.z,u.w
    a.x += (float)h0[0]; a.y += (float)h0[1]; a.z += (float)h0[2]; a.w += (float)h0[3];
    b.x += (float)h1[0]; b.y += (float)h1[1]; b.z += (float)h1[2]; b.w += (float)h1[3];
}

__device__ __forceinline__ uint2 packh4(const float4& v) {
    h4 h;
    h[0] = (_Float16)v.x; h[1] = (_Float16)v.y;
    h[2] = (_Float16)v.z; h[3] = (_Float16)v.w;
    return *(uint2*)&h;
}

__device__ __forceinline__ void xor_reduce8(float4& a, float4& b, int mask) {
    a.x += __shfl_xor(a.x, mask, 64);
    a.y += __shfl_xor(a.y, mask, 64);
    a.z += __shfl_xor(a.z, mask, 64);
    a.w += __shfl_xor(a.w, mask, 64);
    b.x += __shfl_xor(b.x, mask, 64);
    b.y += __shfl_xor(b.y, mask, 64);
    b.z += __shfl_xor(b.z, mask, 64);
    b.w += __shfl_xor(b.w, mask, 64);
}

// bf16 RNE conversion + back
__device__ __forceinline__ u16 f2bf(float f) {
    u32 u = __float_as_uint(f);
    return (u16)((u + 0x7fffu + ((u >> 16) & 1u)) >> 16);
}
__device__ __forceinline__ float bf2f(u16 h) {
    return __uint_as_float(((u32)h) << 16);
}

// ---------------- prescale: xs slices = fp16(x * dinv) ----------------
// xs layout: [4 slices][NN][16 fp16] (32 B rows)
__global__ __launch_bounds__(256) void k_prescale(const float* __restrict__ x,
                                                  const float* __restrict__ dinv,
                                                  u16* __restrict__ xs) {
    int i = blockIdx.x * 256 + threadIdx.x;  // float4 chunk index
    if (i >= NN * 16) return;
    int n = i >> 4;
    int k4 = i & 15;           // 4-feature group 0..15
    int q = k4 >> 2;           // slice 0..3
    float di = dinv[n];
    uint2 v = packh4(scale4(((const float4*)x)[i], di));
    ((uint2*)xs)[((size_t)q * NN + n) * 4 + (k4 & 3)] = v;
}

// ---------------- layer-1 sliced gather ----------------
// Slice s pinned to XCDs {2s,2s+1} via blockIdx%8; each XCD takes one node
// half. Lane map: node=lane>>3 (8/wave), es=(lane>>1)&3, half=lane&1 (16B).
// agg layout: [4][NN][16] f32.
__global__ __launch_bounds__(256) void k_gather1s(const int* __restrict__ rowptr,
                                                  const int* __restrict__ colb,
                                                  const u16* __restrict__ xs,
                                                  const float* __restrict__ dinv,
                                                  float* __restrict__ agg) {
    int bid = blockIdx.x;
    int sh = bid & 7;
    int s = sh >> 1, h = sh & 1;
    int tid = threadIdx.x;
    int lane = tid & 63;
    int wv = tid >> 6;
    int n = h * NH + (bid >> 3) * 32 + wv * 8 + (lane >> 3);
    if (n >= (h + 1) * NH) return;
    int half = lane & 1;
    int es = (lane >> 1) & 3;
    int r0 = rowptr[n], r1 = rowptr[n + 1];
    const char* base = (const char*)xs + (size_t)s * NN * 32 + half * 16;
    float4 a{0, 0, 0, 0}, b{0, 0, 0, 0};
    if (es == 0) addh8(a, b, *(const uint4*)(base + (size_t)n * 32));  // self loop
    int e = r0 + es;
    for (; e + 4 < r1; e += 8) {
        int c0 = colb[e];
        int c1 = colb[e + 4];
        uint4 v0 = *(const uint4*)(base + c0);
        uint4 v1 = *(const uint4*)(base + c1);
        addh8(a, b, v0);
        addh8(a, b, v1);
    }
    for (; e < r1; e += 4)
        addh8(a, b, *(const uint4*)(base + colb[e]));
    xor_reduce8(a, b, 2);
    xor_reduce8(a, b, 4);
    if (es == 0) {
        float di = dinv[n];
        float* ag = agg + ((size_t)s * NN + n) * 16 + half * 8;
        *(float4*)ag = scale4(a, di);
        *(float4*)(ag + 4) = scale4(b, di);
    }
}

// ---------------- weight pre-split into MFMA B-fragment order ----------------
// B-fragment (16x16x32 bf16): lane l holds B[k][col], col=l&15, k=(l>>4)*8+j.
// W1 frags: [(s*8+t)*64 + l]*8 + j  (s: k-step 0..1, t: n-tile 0..7)
// W2 frags: [(s*4+t)*64 + l]*8 + j  (s: k-step 0..3, t: n-tile 0..3)
__global__ __launch_bounds__(256) void k_splitW(const float* __restrict__ W1,
                                                const float* __restrict__ W2,
                                                u16* __restrict__ W1h, u16* __restrict__ W1l,
                                                u16* __restrict__ W2h, u16* __restrict__ W2l) {
    int i = blockIdx.x * 256 + threadIdx.x;  // 0..8191
    if (i >= 8192) return;
    int j = i & 7;
    int l = (i >> 3) & 63;
    int ts = i >> 9;                 // 0..15
    int kf = ((l >> 4) << 3) + j;    // k within 32-step
    int cl = l & 15;
    {   // W1 [64][128]: ts = s*8 + t
        int s = ts >> 3, t = ts & 7;
        float w = W1[(s * 32 + kf) * D1 + t * 16 + cl];
        u16 h = f2bf(w);
        W1h[i] = h;
        W1l[i] = f2bf(w - bf2f(h));
    }
    {   // W2 [128][64]: ts = s*4 + t
        int s = ts >> 2, t = ts & 3;
        float w = W2[(s * 32 + kf) * D2 + t * 16 + cl];
        u16 h = f2bf(w);
        W2h[i] = h;
        W2l[i] = f2bf(w - bf2f(h));
    }
}

// ---------------- fused GEMM1 + GEMM2 via split-bf16 MFMA ----------------
// h1 = relu(agg @ W1 + b1)   (64 -> 128, packed hi/lo bf16 in LDS)
// y2 slices = fp16((h1 @ W2) * dinv)  (128 -> 64), layout [4][NN][16]
// agg read is slice-major: k = q*16 + c  ->  agg[(q*NN+n)*16 + c].
__global__ __launch_bounds__(256) void k_gemm12(const float* __restrict__ agg,
                                                const u16* __restrict__ W1h,
                                                const u16* __restrict__ W1l,
                                                const float* __restrict__ b1,
                                                const u16* __restrict__ W2h,
                                                const u16* __restrict__ W2l,
                                                const float* __restrict__ dinv,
                                                u16* __restrict__ y2) {
    __shared__ u32 h1s[64 * H1STRIDE];  // packed (hi | lo<<16), 33.8 KB
    int tid = threadIdx.x;
    int l = tid & 63;
    int wv = tid >> 6;
    int n_base = blockIdx.x * 64;
    int row_a = l & 15;           // A-operand row within 16-tile
    int kg = (l >> 4) << 3;       // k offset within 32-step: 0,8,16,24
    int crow = (l >> 4) * 4;      // C/D row base: (lane>>4)*4

    // ---- phase A: h1 = relu(agg @ W1 + b1) ----
    short8 Ah[2], Al[2];
#pragma unroll
    for (int s = 0; s < 2; ++s) {
        int an = n_base + wv * 16 + row_a;
        if (an >= NN) an = NN - 1;  // clamp: dup rows, outputs discarded
        int q = (s * 32 + kg) >> 4;      // agg slice
        int off = kg & 8;                // col offset within slice
        const float* ap = agg + ((size_t)q * NN + an) * 16 + off;
        f32x4 v0 = *(const f32x4*)ap;
        f32x4 v1 = *(const f32x4*)(ap + 4);
#pragma unroll
        for (int j = 0; j < 4; ++j) {
            u16 h0 = f2bf(v0[j]);
            Ah[s][j] = (short)h0;
            Al[s][j] = (short)f2bf(v0[j] - bf2f(h0));
            u16 h1b = f2bf(v1[j]);
            Ah[s][j + 4] = (short)h1b;
            Al[s][j + 4] = (short)f2bf(v1[j] - bf2f(h1b));
        }
    }
#pragma unroll
    for (int t = 0; t < 8; ++t) {
        f32x4 acc = {0.f, 0.f, 0.f, 0.f};
#pragma unroll
        for (int s = 0; s < 2; ++s) {
            short8 Bh = *(const short8*)(W1h + ((size_t)(s * 8 + t) * 64 + l) * 8);
            short8 Bl = *(const short8*)(W1l + ((size_t)(s * 8 + t) * 64 + l) * 8);
            acc = __builtin_amdgcn_mfma_f32_16x16x32_bf16(Ah[s], Bh, acc, 0, 0, 0);
            acc = __builtin_amdgcn_mfma_f32_16x16x32_bf16(Ah[s], Bl, acc, 0, 0, 0);
            acc = __builtin_amdgcn_mfma_f32_16x16x32_bf16(Al[s], Bh, acc, 0, 0, 0);
        }
        // epilogue: +b1, relu, split-pack to LDS (C/D: row=(l>>4)*4+r, col=l&15)
        float bb = b1[t * 16 + (l & 15)];
        int kcol = t * 16 + (l & 15);  // h1 feature index = GEMM2 k
#pragma unroll
        for (int r = 0; r < 4; ++r) {
            int row = wv * 16 + crow + r;  // node row in 64-tile
            float v = fmaxf(acc[r] + bb, 0.f);
            u16 h = f2bf(v);
            u16 lo = f2bf(v - bf2f(h));
            h1s[row * H1STRIDE + kcol] = (u32)h | ((u32)lo << 16);
        }
    }
    __syncthreads();

    // ---- phase B: y2 slices = fp16((h1 @ W2) * dinv) ----
    short8 A2h[4], A2l[4];
#pragma unroll
    for (int s = 0; s < 4; ++s) {
        int row = wv * 16 + row_a;
        const u32* hp = &h1s[row * H1STRIDE + s * 32 + kg];
        uint4 p0 = *(const uint4*)hp;
        uint4 p1 = *(const uint4*)(hp + 4);
        u32 pv[8] = {p0.x, p0.y, p0.z, p0.w, p1.x, p1.y, p1.z, p1.w};
#pragma unroll
        for (int j = 0; j < 8; ++j) {
            A2h[s][j] = (short)(pv[j] & 0xffffu);
            A2l[s][j] = (short)(pv[j] >> 16);
        }
    }
#pragma unroll
    for (int t = 0; t < 4; ++t) {
        f32x4 acc = {0.f, 0.f, 0.f, 0.f};
#pragma unroll
        for (int s = 0; s < 4; ++s) {
            short8 Bh = *(const short8*)(W2h + ((size_t)(s * 4 + t) * 64 + l) * 8);
            short8 Bl = *(const short8*)(W2l + ((size_t)(s * 4 + t) * 64 + l) * 8);
            acc = __builtin_amdgcn_mfma_f32_16x16x32_bf16(A2h[s], Bh, acc, 0, 0, 0);
            acc = __builtin_amdgcn_mfma_f32_16x16x32_bf16(A2h[s], Bl, acc, 0, 0, 0);
            acc = __builtin_amdgcn_mfma_f32_16x16x32_bf16(A2l[s], Bh, acc, 0, 0, 0);
        }
        // t == 16-feature slice of y2
#pragma unroll
        for (int r = 0; r < 4; ++r) {
            int n = n_base + wv * 16 + crow + r;
            if (n < NN) {
                _Float16 hf = (_Float16)(acc[r] * dinv[n]);
                y2[((size_t)t * NN + n) * 16 + (l & 15)] = *(u16*)&hf;
            }
        }
    }
}

// ---------------- layer-2 sliced gather + per-slice partial FC head ----------------
// partial[s][n] = sum_{c in slice s} relu((self+sum neigh)*di + b2)[c] * Wfc[c]
__global__ __launch_bounds__(256) void k_gather2s(const int* __restrict__ rowptr,
                                                  const int* __restrict__ colb,
                                                  const u16* __restrict__ y2,
                                                  const float* __restrict__ dinv,
                                                  const float* __restrict__ b2,
                                                  const float* __restrict__ Wfc,
                                                  float* __restrict__ partial) {
    int bid = blockIdx.x;
    int sh = bid & 7;
    int s = sh >> 1, h = sh & 1;
    int tid = threadIdx.x;
    int lane = tid & 63;
    int wv = tid >> 6;
    int n = h * NH + (bid >> 3) * 32 + wv * 8 + (lane >> 3);
    if (n >= (h + 1) * NH) return;
    int half = lane & 1;
    int es = (lane >> 1) & 3;
    int r0 = rowptr[n], r1 = rowptr[n + 1];
    const char* base = (const char*)y2 + (size_t)s * NN * 32 + half * 16;
    float4 a{0, 0, 0, 0}, b{0, 0, 0, 0};
    if (es == 0) addh8(a, b, *(const uint4*)(base + (size_t)n * 32));  // self loop
    int e = r0 + es;
    for (; e + 4 < r1; e += 8) {
        int c0 = colb[e];
        int c1 = colb[e + 4];
        uint4 v0 = *(const uint4*)(base + c0);
        uint4 v1 = *(const uint4*)(base + c1);
        addh8(a, b, v0);
        addh8(a, b, v1);
    }
    for (; e < r1; e += 4)
        addh8(a, b, *(const uint4*)(base + colb[e]));
    xor_reduce8(a, b, 2);
    xor_reduce8(a, b, 4);
    // lanes es==0 hold the 8-feature sums for (slice s, half)
    float di = dinv[n];
    int fo = s * 16 + half * 8;
    float4 b0 = *(const float4*)(b2 + fo);
    float4 b1v = *(const float4*)(b2 + fo + 4);
    float4 w0 = *(const float4*)(Wfc + fo);
    float4 w1 = *(const float4*)(Wfc + fo + 4);
    float p = fmaxf(fmaf(a.x, di, b0.x), 0.f) * w0.x
            + fmaxf(fmaf(a.y, di, b0.y), 0.f) * w0.y
            + fmaxf(fmaf(a.z, di, b0.z), 0.f) * w0.z
            + fmaxf(fmaf(a.w, di, b0.w), 0.f) * w0.w
            + fmaxf(fmaf(b.x, di, b1v.x), 0.f) * w1.x
            + fmaxf(fmaf(b.y, di, b1v.y), 0.f) * w1.y
            + fmaxf(fmaf(b.z, di, b1v.z), 0.f) * w1.z
            + fmaxf(fmaf(b.w, di, b1v.w), 0.f) * w1.w;
    p += __shfl_xor(p, 1, 64);  // combine halves
    if ((lane & 7) == 0 && es == 0) partial[(size_t)s * NN + n] = p;
}

// ---------------- head: sum 4 slice partials + bfc ----------------
__global__ __launch_bounds__(256) void k_head(const float* __restrict__ partial,
                                              const float* __restrict__ bfc,
                                              float* __restrict__ out) {
    int i = blockIdx.x * 256 + threadIdx.x;
    if (i >= NN) return;
    out[i] = partial[i] + partial[NN + i] + partial[2 * NN + i]
           + partial[3 * NN + i] + bfc[0];
}

extern "C" void kernel_launch(void* const* d_in, const int* in_sizes, int n_in,
                              void* d_out, int out_size, void* d_ws, size_t ws_size,
                              hipStream_t stream) {
    const float* x   = (const float*)d_in[0];
    const int*   ei  = (const int*)d_in[1];   // [2, E] int
    const float* W1  = (const float*)d_in[2];
    const float* b1  = (const float*)d_in[3];
    const float* W2  = (const float*)d_in[4];
    const float* b2  = (const float*)d_in[5];
    const float* Wfc = (const float*)d_in[6];
    const float* bfc = (const float*)d_in[7];
    float* out = (float*)d_out;

    const int* src = ei;
    const int* dst = ei + NE;

    char* ws = (char*)d_ws;
    size_t o = 0;
    auto alloc = [&](size_t bytes) { char* p = ws + o; o += (bytes + 255) & ~size_t(255); return p; };
    int*   scratch = (int*)alloc(NN * 4);      // 400 KB: gbcnt + W-split buffers
    int*   rowptr = (int*)alloc((NN + 1) * 4);
    int*   bsum   = (int*)alloc(512 * 4);
    int*   gcur   = (int*)alloc(NB * 4);
    float* dinv   = (float*)alloc(NN * 4);
    int*   col    = (int*)alloc((size_t)NE * 4);
    u16*   xs     = (u16*)alloc((size_t)NN * D0 * 2);    // 12.8 MB fp16 (4 slices)
    float* agg1x  = (float*)alloc((size_t)NN * D0 * 4);  // 25.6 MB fp32 (4 slices)
    u16*   y2     = (u16*)alloc((size_t)NN * D2 * 2);    // 12.8 MB fp16 (4 slices)
    float* partial= (float*)alloc((size_t)NN * 4 * 4);   // 1.6 MB
    unsigned* packed = (unsigned*)agg1x;  // dead before k_gather1s writes agg
    // carve scratch: bucket counts (512 ints) then the 4 x 16 KB weight splits
    int* gbcnt = scratch;
    u16* W1h = (u16*)(scratch + 512);
    u16* W1l = W1h + 8192;
    u16* W2h = W1l + 8192;
    u16* W2l = W2h + 8192;

    const int NT = (NE + TILE - 1) / TILE;  // 196 tiles
    const int GB = 8 * ((NH + 31) / 32);    // 12504 blocks: slice-pinned gathers

    k_zero_b    <<<2, 256, 0, stream>>>(gbcnt);
    k_splitW    <<<32, 256, 0, stream>>>(W1, W2, W1h, W1l, W2h, W2l);
    k_bcount    <<<NT, 256, 0, stream>>>(dst, gbcnt);
    k_scan_bsum <<<1, 512, 0, stream>>>(gbcnt, bsum, gcur);
    k_part      <<<NT, 256, 0, stream>>>(src, dst, gcur, packed);
    k_bucket    <<<NB, 256, 0, stream>>>(bsum, packed, rowptr, dinv, col);
    k_prescale  <<<(NN * 16 + 255) / 256, 256, 0, stream>>>(x, dinv, xs);

    k_gather1s  <<<GB, 256, 0, stream>>>(rowptr, col, xs, dinv, agg1x);
    k_gemm12    <<<(NN + 63) / 64, 256, 0, stream>>>(agg1x, W1h, W1l, b1, W2h, W2l, dinv, y2);
    k_gather2s  <<<GB, 256, 0, stream>>>(rowptr, col, y2, dinv, b2, Wfc, partial);
    k_head      <<<(NN + 255) / 256, 256, 0, stream>>>(partial, bfc, out);
}